// Round 1
// baseline (2697.915 us; speedup 1.0000x reference)
//
#include <hip/hip_runtime.h>
#include <cstdint>
#include <cstddef>

// Problem constants
#define T_TOK 4096      // tokens = 2*2048
#define DIM   1024
#define NEXP  8
#define HID   2730
#define HP    2736      // padded hidden (divisible by 16)
#define NPAIR (T_TOK*2)

// ws layout (bytes)
#define OFF_CNT   0UL                          // 8 ints (zeroed)
#define OFF_USE   64UL                         // 8 floats (zeroed)
#define OFF_Z     96UL                         // 1 float (zeroed)
#define OFF_LIST  256UL                        // 8*4096 ints: (t<<1)|k per expert slot
#define OFF_PAIRW 131584UL                     // 8192 floats: combine weight per pair
#define OFF_H     164352UL                     // 8192*HP floats: silu(g)*u
#define OFF_OP    (OFF_H + (size_t)NPAIR*HP*4) // 8192*1024 floats: per-pair down-proj

// ---------------------------------------------------------------------------
// Router: one 64-lane wave per token. Computes 8 logits, full softmax (for
// aux losses), top-2 softmax weights, appends token to expert lists.
// ---------------------------------------------------------------------------
__global__ __launch_bounds__(256) void router_kernel(
    const float* __restrict__ x, const float* __restrict__ rw,
    int* __restrict__ counts, float* __restrict__ usage, float* __restrict__ zacc,
    int* __restrict__ lists, float* __restrict__ pairw)
{
    __shared__ float s_rw[DIM * NEXP];   // 32 KB
    __shared__ float s_use[NEXP];
    __shared__ float s_z;
    const int tid = threadIdx.x;
    for (int i = tid; i < DIM * NEXP; i += 256) s_rw[i] = rw[i];
    if (tid < NEXP) s_use[tid] = 0.f;
    if (tid == NEXP) s_z = 0.f;
    __syncthreads();

    const int wave = tid >> 6, lane = tid & 63;
    const int t = blockIdx.x * 4 + wave;

    float acc[NEXP];
    #pragma unroll
    for (int e = 0; e < NEXP; ++e) acc[e] = 0.f;
    #pragma unroll
    for (int j = 0; j < DIM / 64; ++j) {
        const int d = j * 64 + lane;
        const float xv = x[(size_t)t * DIM + d];
        #pragma unroll
        for (int e = 0; e < NEXP; ++e) acc[e] = fmaf(xv, s_rw[d * NEXP + e], acc[e]);
    }
    #pragma unroll
    for (int e = 0; e < NEXP; ++e) {
        float v = acc[e];
        for (int off = 32; off > 0; off >>= 1) v += __shfl_down(v, off, 64);
        acc[e] = v;
    }
    if (lane == 0) {
        float l[NEXP];
        #pragma unroll
        for (int e = 0; e < NEXP; ++e) l[e] = acc[e];
        // full softmax + logsumexp for aux losses
        float m = l[0];
        #pragma unroll
        for (int e = 1; e < NEXP; ++e) m = fmaxf(m, l[e]);
        float se = 0.f;
        #pragma unroll
        for (int e = 0; e < NEXP; ++e) se += __expf(l[e] - m);
        const float lse = m + __logf(se);
        #pragma unroll
        for (int e = 0; e < NEXP; ++e) atomicAdd(&s_use[e], __expf(l[e] - m) / se);
        atomicAdd(&s_z, lse * lse);
        // top-2 (strict > keeps lower index on ties, matching jax.lax.top_k)
        int i0 = 0; float l0 = l[0];
        #pragma unroll
        for (int e = 1; e < NEXP; ++e) if (l[e] > l0) { l0 = l[e]; i0 = e; }
        int i1 = -1; float l1 = -1e30f;
        #pragma unroll
        for (int e = 0; e < NEXP; ++e) if (e != i0 && l[e] > l1) { l1 = l[e]; i1 = e; }
        const float p0 = 1.f / (1.f + __expf(l1 - l0));
        const float p1 = 1.f - p0;
        const int pos0 = atomicAdd(&counts[i0], 1);
        lists[i0 * T_TOK + pos0] = (t << 1);
        const int pos1 = atomicAdd(&counts[i1], 1);
        lists[i1 * T_TOK + pos1] = (t << 1) | 1;
        pairw[2 * t]     = p0;
        pairw[2 * t + 1] = p1;
    }
    __syncthreads();
    if (tid < NEXP) atomicAdd(&usage[tid], s_use[tid]);
    if (tid == NEXP) atomicAdd(zacc, s_z);
}

__global__ void finalize_kernel(const float* __restrict__ usage,
                                const float* __restrict__ zacc,
                                float* __restrict__ out)
{
    if (threadIdx.x == 0 && blockIdx.x == 0) {
        float s = 0.f;
        for (int e = 0; e < NEXP; ++e) {
            const float u = usage[e] / (float)T_TOK;
            s += u * u;
        }
        out[(size_t)T_TOK * DIM]     = (float)NEXP * s;
        out[(size_t)T_TOK * DIM + 1] = zacc[0] / (float)T_TOK;
    }
}

// ---------------------------------------------------------------------------
// GEMM1: h[pair, :] = silu(X_e @ Wg[e]) * (X_e @ Wu[e]).  Tiled 64x64x16 fp32,
// 256 threads, 4x4 outputs/thread for both gate and up (shared A tile).
// ---------------------------------------------------------------------------
__global__ __launch_bounds__(256) void gemm1_kernel(
    const float* __restrict__ x, const float* __restrict__ wg,
    const float* __restrict__ wu, const int* __restrict__ counts,
    const int* __restrict__ lists, float* __restrict__ h)
{
    const int e = blockIdx.z;
    const int cnt = counts[e];
    const int row0 = blockIdx.y * 64;
    if (row0 >= cnt) return;
    const int n0 = blockIdx.x * 64;

    __shared__ float As[16][68];
    __shared__ float Bg[16][68];
    __shared__ float Bu[16][68];
    __shared__ int s_row[64];

    const int tid = threadIdx.x;
    if (tid < 64) {
        const int r = row0 + tid;
        s_row[tid] = (r < cnt) ? lists[e * T_TOK + r] : -1;
    }
    __syncthreads();

    float accg[4][4] = {{0.f}}, accu[4][4] = {{0.f}};
    const int tm = tid >> 4, tn = tid & 15;
    const size_t wbase = (size_t)e * DIM * HID;

    for (int kt = 0; kt < DIM / 16; ++kt) {
        const int k0 = kt * 16;
        {   // A tile: 64 rows x 16 k
            const int ka = tid & 15;
            #pragma unroll
            for (int i = 0; i < 4; ++i) {
                const int m = (tid >> 4) + i * 16;
                const int pr = s_row[m];
                float v = 0.f;
                if (pr >= 0) v = x[(size_t)(pr >> 1) * DIM + k0 + ka];
                As[ka][m] = v;
            }
        }
        {   // B tiles: 16 k x 64 n for gate and up
            const int nb = tid & 63;
            const int n = n0 + nb;
            const bool nv = (n < HID);
            #pragma unroll
            for (int i = 0; i < 4; ++i) {
                const int kb = (tid >> 6) + i * 4;
                float g = 0.f, u = 0.f;
                if (nv) {
                    const size_t off = wbase + (size_t)(k0 + kb) * HID + n;
                    g = wg[off]; u = wu[off];
                }
                Bg[kb][nb] = g; Bu[kb][nb] = u;
            }
        }
        __syncthreads();
        #pragma unroll
        for (int k = 0; k < 16; ++k) {
            const float4 av = *(const float4*)&As[k][tm * 4];
            const float4 gv = *(const float4*)&Bg[k][tn * 4];
            const float4 uv = *(const float4*)&Bu[k][tn * 4];
            const float a[4] = {av.x, av.y, av.z, av.w};
            const float g[4] = {gv.x, gv.y, gv.z, gv.w};
            const float u[4] = {uv.x, uv.y, uv.z, uv.w};
            #pragma unroll
            for (int i = 0; i < 4; ++i)
                #pragma unroll
                for (int j = 0; j < 4; ++j) {
                    accg[i][j] = fmaf(a[i], g[j], accg[i][j]);
                    accu[i][j] = fmaf(a[i], u[j], accu[i][j]);
                }
        }
        __syncthreads();
    }
    // epilogue: silu(g)*u
    #pragma unroll
    for (int i = 0; i < 4; ++i) {
        const int pr = s_row[tm * 4 + i];
        if (pr < 0) continue;
        float* hrow = h + (size_t)pr * HP;
        #pragma unroll
        for (int j = 0; j < 4; ++j) {
            const int n = n0 + tn * 4 + j;
            if (n < HID) {
                const float g = accg[i][j];
                const float s = g / (1.f + __expf(-g));
                hrow[n] = s * accu[i][j];
            }
        }
    }
}

// ---------------------------------------------------------------------------
// GEMM2: op[pair, :] = h[pair, :] @ Wd[e].  Tiled 64x64x16 fp32.
// ---------------------------------------------------------------------------
__global__ __launch_bounds__(256) void gemm2_kernel(
    const float* __restrict__ h, const float* __restrict__ wd,
    const int* __restrict__ counts, const int* __restrict__ lists,
    float* __restrict__ op)
{
    const int e = blockIdx.z;
    const int cnt = counts[e];
    const int row0 = blockIdx.y * 64;
    if (row0 >= cnt) return;
    const int n0 = blockIdx.x * 64;

    __shared__ float As[16][68];
    __shared__ float Bs[16][68];
    __shared__ int s_row[64];

    const int tid = threadIdx.x;
    if (tid < 64) {
        const int r = row0 + tid;
        s_row[tid] = (r < cnt) ? lists[e * T_TOK + r] : -1;
    }
    __syncthreads();

    float acc[4][4] = {{0.f}};
    const int tm = tid >> 4, tn = tid & 15;
    const size_t wbase = (size_t)e * HID * DIM;

    for (int kt = 0; kt < HP / 16; ++kt) {
        const int k0 = kt * 16;
        {
            const int ka = tid & 15;
            const int kk = k0 + ka;
            #pragma unroll
            for (int i = 0; i < 4; ++i) {
                const int m = (tid >> 4) + i * 16;
                const int pr = s_row[m];
                float v = 0.f;
                if (pr >= 0 && kk < HID) v = h[(size_t)pr * HP + kk];
                As[ka][m] = v;
            }
        }
        {
            const int nb = tid & 63;
            #pragma unroll
            for (int i = 0; i < 4; ++i) {
                const int kb = (tid >> 6) + i * 4;
                const int kk = k0 + kb;
                float v = 0.f;
                if (kk < HID) v = wd[wbase + (size_t)kk * DIM + n0 + nb];
                Bs[kb][nb] = v;
            }
        }
        __syncthreads();
        #pragma unroll
        for (int k = 0; k < 16; ++k) {
            const float4 av = *(const float4*)&As[k][tm * 4];
            const float4 bv = *(const float4*)&Bs[k][tn * 4];
            const float a[4] = {av.x, av.y, av.z, av.w};
            const float b[4] = {bv.x, bv.y, bv.z, bv.w};
            #pragma unroll
            for (int i = 0; i < 4; ++i)
                #pragma unroll
                for (int j = 0; j < 4; ++j)
                    acc[i][j] = fmaf(a[i], b[j], acc[i][j]);
        }
        __syncthreads();
    }
    #pragma unroll
    for (int i = 0; i < 4; ++i) {
        const int pr = s_row[tm * 4 + i];
        if (pr < 0) continue;
        float4 v;
        v.x = acc[i][0]; v.y = acc[i][1]; v.z = acc[i][2]; v.w = acc[i][3];
        *(float4*)&op[(size_t)pr * DIM + n0 + tn * 4] = v;
    }
}

// ---------------------------------------------------------------------------
// Combine: out[t] = w0*op[2t] + w1*op[2t+1]
// ---------------------------------------------------------------------------
__global__ __launch_bounds__(256) void combine_kernel(
    const float* __restrict__ op, const float* __restrict__ pairw,
    float* __restrict__ out)
{
    const int f = blockIdx.x * 256 + threadIdx.x;   // over T*D/4 float4s
    const int t = f >> 8;                            // 256 float4 per token row
    const int c = f & 255;
    const float w0 = pairw[2 * t], w1 = pairw[2 * t + 1];
    const float4* o = (const float4*)op;
    const float4 a = o[(size_t)(2 * t) * (DIM / 4) + c];
    const float4 b = o[(size_t)(2 * t + 1) * (DIM / 4) + c];
    float4 r;
    r.x = w0 * a.x + w1 * b.x;
    r.y = w0 * a.y + w1 * b.y;
    r.z = w0 * a.z + w1 * b.z;
    r.w = w0 * a.w + w1 * b.w;
    ((float4*)out)[f] = r;
}

extern "C" void kernel_launch(void* const* d_in, const int* in_sizes, int n_in,
                              void* d_out, int out_size, void* d_ws, size_t ws_size,
                              hipStream_t stream)
{
    const float* x  = (const float*)d_in[0];
    const float* rw = (const float*)d_in[1];
    const float* wg = (const float*)d_in[2];
    const float* wu = (const float*)d_in[3];
    const float* wd = (const float*)d_in[4];
    float* out = (float*)d_out;
    char* ws = (char*)d_ws;

    int*   counts = (int*)(ws + OFF_CNT);
    float* usage  = (float*)(ws + OFF_USE);
    float* zacc   = (float*)(ws + OFF_Z);
    int*   lists  = (int*)(ws + OFF_LIST);
    float* pairw  = (float*)(ws + OFF_PAIRW);
    float* hbuf   = (float*)(ws + OFF_H);
    float* op     = (float*)(ws + OFF_OP);

    // zero counts + loss accumulators (ws is poisoned 0xAA before each launch)
    hipMemsetAsync(ws, 0, 128, stream);

    router_kernel<<<T_TOK / 4, 256, 0, stream>>>(x, rw, counts, usage, zacc, lists, pairw);
    finalize_kernel<<<1, 64, 0, stream>>>(usage, zacc, out);

    dim3 g1((HID + 63) / 64, T_TOK / 64, NEXP);
    gemm1_kernel<<<g1, 256, 0, stream>>>(x, wg, wu, counts, lists, hbuf);

    dim3 g2(DIM / 64, T_TOK / 64, NEXP);
    gemm2_kernel<<<g2, 256, 0, stream>>>(hbuf, wd, counts, lists, op);

    combine_kernel<<<(T_TOK * DIM / 4) / 256, 256, 0, stream>>>(op, pairw, out);
}

// Round 2
// 706.974 us; speedup vs baseline: 3.8161x; 3.8161x over previous
//
#include <hip/hip_runtime.h>
#include <cstdint>
#include <cstddef>

// Problem constants
#define T_TOK 4096
#define DIM   1024
#define NEXP  8
#define HID   2730
#define HP2   2816          // hidden padded to 88*32 = 22*128
#define NB1   5632          // 2*HP2 rows (gate || up) in transposed B1
#define NPAIR (T_TOK*2)

typedef __attribute__((ext_vector_type(8))) short short8;
typedef __attribute__((ext_vector_type(4))) float f32x4;

// ws layout (bytes)
#define OFF_CNT   0UL
#define OFF_USE   64UL
#define OFF_Z     96UL
#define OFF_LIST  256UL                                   // 8*4096 ints
#define OFF_PAIRW 131328UL                                // 8192 floats
#define OFF_XB    164096UL                                // 4096*1024 bf16
#define OFF_H     (OFF_XB + 8388608UL)                    // 8192*2816 bf16
#define OFF_B2    (OFF_H + 46137344UL)                    // 8*1024*2816 bf16
#define OFF_B1    (OFF_B2 + 46137344UL)                   // 8*5632*1024 bf16
#define OFF_OP    OFF_B1                                  // overlay: 8192*1024 f32 (B1 dead after gemm1)

__device__ __forceinline__ unsigned short f2bf(float f) {
    unsigned u = __float_as_uint(f);
    return (unsigned short)((u + 0x7FFFu + ((u >> 16) & 1u)) >> 16);
}

__device__ __forceinline__ void load_lds16(const void* g, void* l) {
    __builtin_amdgcn_global_load_lds(
        (const __attribute__((address_space(1))) void*)g,
        (__attribute__((address_space(3))) void*)l, 16, 0, 0);
}

// ---------------------------------------------------------------------------
// Router (fp32, exact): one wave per token; top-2 softmax; aux losses; lists.
// ---------------------------------------------------------------------------
__global__ __launch_bounds__(256) void router_kernel(
    const float* __restrict__ x, const float* __restrict__ rw,
    int* __restrict__ counts, float* __restrict__ usage, float* __restrict__ zacc,
    int* __restrict__ lists, float* __restrict__ pairw)
{
    __shared__ float s_rw[DIM * NEXP];
    __shared__ float s_use[NEXP];
    __shared__ float s_z;
    const int tid = threadIdx.x;
    for (int i = tid; i < DIM * NEXP; i += 256) s_rw[i] = rw[i];
    if (tid < NEXP) s_use[tid] = 0.f;
    if (tid == NEXP) s_z = 0.f;
    __syncthreads();

    const int wave = tid >> 6, lane = tid & 63;
    const int t = blockIdx.x * 4 + wave;

    float acc[NEXP];
    #pragma unroll
    for (int e = 0; e < NEXP; ++e) acc[e] = 0.f;
    #pragma unroll
    for (int j = 0; j < DIM / 64; ++j) {
        const int d = j * 64 + lane;
        const float xv = x[(size_t)t * DIM + d];
        #pragma unroll
        for (int e = 0; e < NEXP; ++e) acc[e] = fmaf(xv, s_rw[d * NEXP + e], acc[e]);
    }
    #pragma unroll
    for (int e = 0; e < NEXP; ++e) {
        float v = acc[e];
        for (int off = 32; off > 0; off >>= 1) v += __shfl_down(v, off, 64);
        acc[e] = v;
    }
    if (lane == 0) {
        float l[NEXP];
        #pragma unroll
        for (int e = 0; e < NEXP; ++e) l[e] = acc[e];
        float m = l[0];
        #pragma unroll
        for (int e = 1; e < NEXP; ++e) m = fmaxf(m, l[e]);
        float se = 0.f;
        #pragma unroll
        for (int e = 0; e < NEXP; ++e) se += __expf(l[e] - m);
        const float lse = m + __logf(se);
        #pragma unroll
        for (int e = 0; e < NEXP; ++e) atomicAdd(&s_use[e], __expf(l[e] - m) / se);
        atomicAdd(&s_z, lse * lse);
        int i0 = 0; float l0 = l[0];
        #pragma unroll
        for (int e = 1; e < NEXP; ++e) if (l[e] > l0) { l0 = l[e]; i0 = e; }
        int i1 = -1; float l1 = -1e30f;
        #pragma unroll
        for (int e = 0; e < NEXP; ++e) if (e != i0 && l[e] > l1) { l1 = l[e]; i1 = e; }
        const float p0 = 1.f / (1.f + __expf(l1 - l0));
        const float p1 = 1.f - p0;
        const int pos0 = atomicAdd(&counts[i0], 1);
        lists[i0 * T_TOK + pos0] = (t << 1);
        const int pos1 = atomicAdd(&counts[i1], 1);
        lists[i1 * T_TOK + pos1] = (t << 1) | 1;
        pairw[2 * t]     = p0;
        pairw[2 * t + 1] = p1;
    }
    __syncthreads();
    if (tid < NEXP) atomicAdd(&usage[tid], s_use[tid]);
    if (tid == NEXP) atomicAdd(zacc, s_z);
}

__global__ void finalize_kernel(const float* __restrict__ usage,
                                const float* __restrict__ zacc,
                                float* __restrict__ out)
{
    if (threadIdx.x == 0 && blockIdx.x == 0) {
        float s = 0.f;
        for (int e = 0; e < NEXP; ++e) {
            const float u = usage[e] / (float)T_TOK;
            s += u * u;
        }
        out[(size_t)T_TOK * DIM]     = (float)NEXP * s;
        out[(size_t)T_TOK * DIM + 1] = zacc[0] / (float)T_TOK;
    }
}

// ---------------------------------------------------------------------------
// Conversions
// ---------------------------------------------------------------------------
struct __align__(8) us4 { unsigned short x, y, z, w; };

__global__ __launch_bounds__(256) void conv_x_kernel(const float* __restrict__ x,
                                                     unsigned short* __restrict__ xb)
{
    const int f = blockIdx.x * 256 + threadIdx.x;   // over T*D/4
    const float4 v = ((const float4*)x)[f];
    us4 o; o.x = f2bf(v.x); o.y = f2bf(v.y); o.z = f2bf(v.z); o.w = f2bf(v.w);
    ((us4*)xb)[f] = o;
}

// wg,wu [e][k=1024][h=2730] f32  ->  B1 [e][n][k] bf16, n in [0,5632)
// rows [0,2816) = gate (0-padded past 2730), rows [2816,5632) = up.
__global__ __launch_bounds__(256) void conv_w1_kernel(
    const float* __restrict__ wg, const float* __restrict__ wu,
    unsigned short* __restrict__ B1)
{
    __shared__ float tg[32][33];
    __shared__ float tu[32][33];
    const int e = blockIdx.z;
    const int h0 = blockIdx.x * 32;
    const int k0 = blockIdx.y * 32;
    const int tid = threadIdx.x;
    const int c = tid & 31, r = tid >> 5;
    const size_t wb = (size_t)e * DIM * HID;
    #pragma unroll
    for (int i = 0; i < 4; ++i) {
        const int kk = r + i * 8;
        const int h = h0 + c;
        float g = 0.f, u = 0.f;
        if (h < HID) {
            const size_t off = wb + (size_t)(k0 + kk) * HID + h;
            g = wg[off]; u = wu[off];
        }
        tg[kk][c] = g; tu[kk][c] = u;
    }
    __syncthreads();
    #pragma unroll
    for (int i = 0; i < 4; ++i) {
        const int nn = r + i * 8;                // local n (h index)
        const size_t rowg = ((size_t)e * NB1 + h0 + nn) * DIM + k0 + c;
        const size_t rowu = ((size_t)e * NB1 + HP2 + h0 + nn) * DIM + k0 + c;
        B1[rowg] = f2bf(tg[c][nn]);
        B1[rowu] = f2bf(tu[c][nn]);
    }
}

// wd [e][h=2730][d=1024] f32 -> B2 [e][n=d][k=h] bf16, k padded to 2816 w/ 0
__global__ __launch_bounds__(256) void conv_w2_kernel(
    const float* __restrict__ wd, unsigned short* __restrict__ B2)
{
    __shared__ float t2[32][33];
    const int e = blockIdx.z;
    const int h0 = blockIdx.x * 32;   // k dim
    const int d0 = blockIdx.y * 32;   // n dim
    const int tid = threadIdx.x;
    const int c = tid & 31, r = tid >> 5;
    const size_t wb = (size_t)e * HID * DIM;
    #pragma unroll
    for (int i = 0; i < 4; ++i) {
        const int kk = r + i * 8;
        const int h = h0 + kk;
        float v = 0.f;
        if (h < HID) v = wd[wb + (size_t)h * DIM + d0 + c];
        t2[kk][c] = v;
    }
    __syncthreads();
    #pragma unroll
    for (int i = 0; i < 4; ++i) {
        const int nn = r + i * 8;                // local d
        B2[((size_t)e * DIM + d0 + nn) * HP2 + h0 + c] = f2bf(t2[c][nn]);
    }
}

// ---------------------------------------------------------------------------
// GEMM1 (MFMA): h[pr,:] = silu(Xe @ Wg) * (Xe @ Wu), 128x128x32 tiles,
// gate+up fused in one block (same n-range). A gathered via pair lists.
// ---------------------------------------------------------------------------
__global__ __launch_bounds__(256, 2) void gemm1_kernel(
    const unsigned short* __restrict__ xb, const unsigned short* __restrict__ B1,
    const int* __restrict__ counts, const int* __restrict__ lists,
    unsigned short* __restrict__ h)
{
    const int e = blockIdx.z;
    const int cnt = counts[e];
    const int row0 = blockIdx.y * 128;
    if (row0 >= cnt) return;
    const int n0 = blockIdx.x * 128;

    __shared__ unsigned short sA[128 * 32];
    __shared__ unsigned short sBg[128 * 32];
    __shared__ unsigned short sBu[128 * 32];
    __shared__ int s_pr[128];

    const int tid = threadIdx.x;
    const int w = tid >> 6, lane = tid & 63;
    if (tid < 128) {
        const int r = row0 + tid;
        s_pr[tid] = (r < cnt) ? lists[e * T_TOK + r] : -1;
    }
    __syncthreads();

    // staging assignment: 16B block b = tid (rows 0..63) and tid+256 (rows 64..127)
    const int rA = tid >> 2, kb = tid & 3;
    const int pr0 = s_pr[rA], pr1 = s_pr[rA + 64];
    const unsigned short* agp0 = xb + (size_t)(max(pr0, 0) >> 1) * DIM + kb * 8;
    const unsigned short* agp1 = xb + (size_t)(max(pr1, 0) >> 1) * DIM + kb * 8;
    const unsigned short* bgp0 = B1 + ((size_t)e * NB1 + n0 + rA) * DIM + kb * 8;
    const unsigned short* bgp1 = bgp0 + (size_t)64 * DIM;
    const unsigned short* bup0 = B1 + ((size_t)e * NB1 + HP2 + n0 + rA) * DIM + kb * 8;
    const unsigned short* bup1 = bup0 + (size_t)64 * DIM;

    char* sAb = (char*)sA; char* sBgb = (char*)sBg; char* sBub = (char*)sBu;
    void* ldsA0 = sAb + w * 1024;        void* ldsA1 = sAb + 4096 + w * 1024;
    void* ldsG0 = sBgb + w * 1024;       void* ldsG1 = sBgb + 4096 + w * 1024;
    void* ldsU0 = sBub + w * 1024;       void* ldsU1 = sBub + 4096 + w * 1024;

    f32x4 accg[4][4], accu[4][4];
    #pragma unroll
    for (int i = 0; i < 4; ++i)
        #pragma unroll
        for (int j = 0; j < 4; ++j) { accg[i][j] = (f32x4)0.f; accu[i][j] = (f32x4)0.f; }

    const int wm = w & 1, wn = w >> 1;
    const int fm = lane & 15, fq = lane >> 4;

    for (int kt = 0; kt < DIM / 32; ++kt) {
        const int k0 = kt * 32;
        load_lds16(agp0 + k0, ldsA0);
        load_lds16(agp1 + k0, ldsA1);
        load_lds16(bgp0 + k0, ldsG0);
        load_lds16(bgp1 + k0, ldsG1);
        load_lds16(bup0 + k0, ldsU0);
        load_lds16(bup1 + k0, ldsU1);
        __syncthreads();

        short8 a[4], bg[4], bu[4];
        #pragma unroll
        for (int i = 0; i < 4; ++i) {
            a[i]  = *(const short8*)&sA[(wm * 64 + i * 16 + fm) * 32 + fq * 8];
            bg[i] = *(const short8*)&sBg[(wn * 64 + i * 16 + fm) * 32 + fq * 8];
            bu[i] = *(const short8*)&sBu[(wn * 64 + i * 16 + fm) * 32 + fq * 8];
        }
        #pragma unroll
        for (int i = 0; i < 4; ++i)
            #pragma unroll
            for (int j = 0; j < 4; ++j) {
                accg[i][j] = __builtin_amdgcn_mfma_f32_16x16x32_bf16(a[i], bg[j], accg[i][j], 0, 0, 0);
                accu[i][j] = __builtin_amdgcn_mfma_f32_16x16x32_bf16(a[i], bu[j], accu[i][j], 0, 0, 0);
            }
        __syncthreads();
    }

    #pragma unroll
    for (int i = 0; i < 4; ++i)
        #pragma unroll
        for (int reg = 0; reg < 4; ++reg) {
            const int rl = wm * 64 + i * 16 + fq * 4 + reg;
            const int pr = s_pr[rl];
            if (pr < 0) continue;
            unsigned short* hrow = h + (size_t)pr * HP2;
            #pragma unroll
            for (int j = 0; j < 4; ++j) {
                const int n = n0 + wn * 64 + j * 16 + fm;
                const float g = accg[i][j][reg];
                const float u = accu[i][j][reg];
                const float s = g / (1.f + __expf(-g));
                hrow[n] = f2bf(s * u);
            }
        }
}

// ---------------------------------------------------------------------------
// GEMM2 (MFMA): op[pr,:] = h[pr,:] @ Wd^T-layout, 128x128x32, K=2816
// ---------------------------------------------------------------------------
__global__ __launch_bounds__(256, 2) void gemm2_kernel(
    const unsigned short* __restrict__ h, const unsigned short* __restrict__ B2,
    const int* __restrict__ counts, const int* __restrict__ lists,
    float* __restrict__ op)
{
    const int e = blockIdx.z;
    const int cnt = counts[e];
    const int row0 = blockIdx.y * 128;
    if (row0 >= cnt) return;
    const int n0 = blockIdx.x * 128;

    __shared__ unsigned short sA[128 * 32];
    __shared__ unsigned short sB[128 * 32];
    __shared__ int s_pr[128];

    const int tid = threadIdx.x;
    const int w = tid >> 6, lane = tid & 63;
    if (tid < 128) {
        const int r = row0 + tid;
        s_pr[tid] = (r < cnt) ? lists[e * T_TOK + r] : -1;
    }
    __syncthreads();

    const int rA = tid >> 2, kb = tid & 3;
    const int pr0 = s_pr[rA], pr1 = s_pr[rA + 64];
    const unsigned short* agp0 = h + (size_t)max(pr0, 0) * HP2 + kb * 8;
    const unsigned short* agp1 = h + (size_t)max(pr1, 0) * HP2 + kb * 8;
    const unsigned short* bp0 = B2 + ((size_t)e * DIM + n0 + rA) * HP2 + kb * 8;
    const unsigned short* bp1 = bp0 + (size_t)64 * HP2;

    char* sAb = (char*)sA; char* sBb = (char*)sB;
    void* ldsA0 = sAb + w * 1024;  void* ldsA1 = sAb + 4096 + w * 1024;
    void* ldsB0 = sBb + w * 1024;  void* ldsB1 = sBb + 4096 + w * 1024;

    f32x4 acc[4][4];
    #pragma unroll
    for (int i = 0; i < 4; ++i)
        #pragma unroll
        for (int j = 0; j < 4; ++j) acc[i][j] = (f32x4)0.f;

    const int wm = w & 1, wn = w >> 1;
    const int fm = lane & 15, fq = lane >> 4;

    for (int kt = 0; kt < HP2 / 32; ++kt) {
        const int k0 = kt * 32;
        load_lds16(agp0 + k0, ldsA0);
        load_lds16(agp1 + k0, ldsA1);
        load_lds16(bp0 + k0, ldsB0);
        load_lds16(bp1 + k0, ldsB1);
        __syncthreads();

        short8 a[4], b[4];
        #pragma unroll
        for (int i = 0; i < 4; ++i) {
            a[i] = *(const short8*)&sA[(wm * 64 + i * 16 + fm) * 32 + fq * 8];
            b[i] = *(const short8*)&sB[(wn * 64 + i * 16 + fm) * 32 + fq * 8];
        }
        #pragma unroll
        for (int i = 0; i < 4; ++i)
            #pragma unroll
            for (int j = 0; j < 4; ++j)
                acc[i][j] = __builtin_amdgcn_mfma_f32_16x16x32_bf16(a[i], b[j], acc[i][j], 0, 0, 0);
        __syncthreads();
    }

    #pragma unroll
    for (int i = 0; i < 4; ++i)
        #pragma unroll
        for (int reg = 0; reg < 4; ++reg) {
            const int rl = wm * 64 + i * 16 + fq * 4 + reg;
            const int pr = s_pr[rl];
            if (pr < 0) continue;
            float* orow = op + (size_t)pr * DIM;
            #pragma unroll
            for (int j = 0; j < 4; ++j) {
                const int n = n0 + wn * 64 + j * 16 + fm;
                orow[n] = acc[i][j][reg];
            }
        }
}

// ---------------------------------------------------------------------------
// Combine: out[t] = w0*op[2t] + w1*op[2t+1]
// ---------------------------------------------------------------------------
__global__ __launch_bounds__(256) void combine_kernel(
    const float* __restrict__ op, const float* __restrict__ pairw,
    float* __restrict__ out)
{
    const int f = blockIdx.x * 256 + threadIdx.x;
    const int t = f >> 8;
    const int c = f & 255;
    const float w0 = pairw[2 * t], w1 = pairw[2 * t + 1];
    const float4* o = (const float4*)op;
    const float4 a = o[(size_t)(2 * t) * (DIM / 4) + c];
    const float4 b = o[(size_t)(2 * t + 1) * (DIM / 4) + c];
    float4 r;
    r.x = w0 * a.x + w1 * b.x;
    r.y = w0 * a.y + w1 * b.y;
    r.z = w0 * a.z + w1 * b.z;
    r.w = w0 * a.w + w1 * b.w;
    ((float4*)out)[f] = r;
}

extern "C" void kernel_launch(void* const* d_in, const int* in_sizes, int n_in,
                              void* d_out, int out_size, void* d_ws, size_t ws_size,
                              hipStream_t stream)
{
    const float* x  = (const float*)d_in[0];
    const float* rw = (const float*)d_in[1];
    const float* wg = (const float*)d_in[2];
    const float* wu = (const float*)d_in[3];
    const float* wd = (const float*)d_in[4];
    float* out = (float*)d_out;
    char* ws = (char*)d_ws;

    int*   counts = (int*)(ws + OFF_CNT);
    float* usage  = (float*)(ws + OFF_USE);
    float* zacc   = (float*)(ws + OFF_Z);
    int*   lists  = (int*)(ws + OFF_LIST);
    float* pairw  = (float*)(ws + OFF_PAIRW);
    unsigned short* xb  = (unsigned short*)(ws + OFF_XB);
    unsigned short* hb  = (unsigned short*)(ws + OFF_H);
    unsigned short* B2  = (unsigned short*)(ws + OFF_B2);
    unsigned short* B1  = (unsigned short*)(ws + OFF_B1);
    float* op = (float*)(ws + OFF_OP);

    hipMemsetAsync(ws, 0, 128, stream);

    router_kernel<<<T_TOK / 4, 256, 0, stream>>>(x, rw, counts, usage, zacc, lists, pairw);
    finalize_kernel<<<1, 64, 0, stream>>>(usage, zacc, out);

    conv_x_kernel<<<(T_TOK * DIM / 4) / 256, 256, 0, stream>>>(x, xb);
    conv_w1_kernel<<<dim3(HP2 / 32, DIM / 32, NEXP), 256, 0, stream>>>(wg, wu, B1);
    conv_w2_kernel<<<dim3(HP2 / 32, DIM / 32, NEXP), 256, 0, stream>>>(wd, B2);

    gemm1_kernel<<<dim3(HP2 / 128, T_TOK / 128, NEXP), 256, 0, stream>>>(xb, B1, counts, lists, hb);
    gemm2_kernel<<<dim3(DIM / 128, T_TOK / 128, NEXP), 256, 0, stream>>>(hb, B2, counts, lists, op);

    combine_kernel<<<(T_TOK * DIM / 4) / 256, 256, 0, stream>>>(op, pairw, out);
}

// Round 3
// 693.600 us; speedup vs baseline: 3.8897x; 1.0193x over previous
//
#include <hip/hip_runtime.h>
#include <cstdint>
#include <cstddef>

// Problem constants
#define T_TOK 4096
#define DIM   1024
#define NEXP  8
#define HID   2730
#define HP2   2816          // hidden padded to 88*32 = 22*128
#define NB1   5632          // 2*HP2 rows (gate || up) in transposed B1
#define NPAIR (T_TOK*2)

typedef __attribute__((ext_vector_type(8))) short short8;
typedef __attribute__((ext_vector_type(4))) float f32x4;

// ws layout (bytes)
#define OFF_CNT   0UL
#define OFF_USE   64UL
#define OFF_Z     96UL
#define OFF_OFFS  160UL                                   // 8 ints (prefix offsets)
#define OFF_LIST  256UL                                   // 8*4096 ints
#define OFF_PAIRW 131328UL                                // 8192 floats
#define OFF_XB    164096UL                                // 4096*1024 bf16
#define OFF_H     (OFF_XB + 8388608UL)                    // 8192*2816 bf16 (slot-compacted)
#define OFF_B2    (OFF_H + 46137344UL)                    // 8*1024*2816 bf16
#define OFF_B1    (OFF_B2 + 46137344UL)                   // 8*5632*1024 bf16
#define OFF_OP    OFF_B1                                  // overlay: 8192*1024 bf16 (B1 dead after gemm1)

__device__ __forceinline__ unsigned short f2bf(float f) {
    unsigned u = __float_as_uint(f);
    return (unsigned short)((u + 0x7FFFu + ((u >> 16) & 1u)) >> 16);
}

__device__ __forceinline__ void load_lds16(const void* g, void* l) {
    __builtin_amdgcn_global_load_lds(
        (const __attribute__((address_space(1))) void*)g,
        (__attribute__((address_space(3))) void*)l, 16, 0, 0);
}

struct __align__(8) us4 { unsigned short x, y, z, w; };

// ---------------------------------------------------------------------------
// Router (fp32, exact) + x->bf16 conversion fused.
// ---------------------------------------------------------------------------
__global__ __launch_bounds__(256) void router_kernel(
    const float* __restrict__ x, const float* __restrict__ rw,
    int* __restrict__ counts, float* __restrict__ usage, float* __restrict__ zacc,
    int* __restrict__ lists, float* __restrict__ pairw,
    unsigned short* __restrict__ xb)
{
    __shared__ float s_rw[DIM * NEXP];
    __shared__ float s_use[NEXP];
    __shared__ float s_z;
    const int tid = threadIdx.x;
    for (int i = tid; i < DIM * NEXP; i += 256) s_rw[i] = rw[i];
    if (tid < NEXP) s_use[tid] = 0.f;
    if (tid == NEXP) s_z = 0.f;
    __syncthreads();

    const int wave = tid >> 6, lane = tid & 63;
    const int t = blockIdx.x * 4 + wave;

    float acc[NEXP];
    #pragma unroll
    for (int e = 0; e < NEXP; ++e) acc[e] = 0.f;
    #pragma unroll
    for (int j = 0; j < DIM / 64; ++j) {
        const int d = j * 64 + lane;
        const float xv = x[(size_t)t * DIM + d];
        xb[(size_t)t * DIM + d] = f2bf(xv);
        #pragma unroll
        for (int e = 0; e < NEXP; ++e) acc[e] = fmaf(xv, s_rw[d * NEXP + e], acc[e]);
    }
    #pragma unroll
    for (int e = 0; e < NEXP; ++e) {
        float v = acc[e];
        for (int off = 32; off > 0; off >>= 1) v += __shfl_down(v, off, 64);
        acc[e] = v;
    }
    if (lane == 0) {
        float l[NEXP];
        #pragma unroll
        for (int e = 0; e < NEXP; ++e) l[e] = acc[e];
        float m = l[0];
        #pragma unroll
        for (int e = 1; e < NEXP; ++e) m = fmaxf(m, l[e]);
        float se = 0.f;
        #pragma unroll
        for (int e = 0; e < NEXP; ++e) se += __expf(l[e] - m);
        const float lse = m + __logf(se);
        #pragma unroll
        for (int e = 0; e < NEXP; ++e) atomicAdd(&s_use[e], __expf(l[e] - m) / se);
        atomicAdd(&s_z, lse * lse);
        int i0 = 0; float l0 = l[0];
        #pragma unroll
        for (int e = 1; e < NEXP; ++e) if (l[e] > l0) { l0 = l[e]; i0 = e; }
        int i1 = -1; float l1 = -1e30f;
        #pragma unroll
        for (int e = 0; e < NEXP; ++e) if (e != i0 && l[e] > l1) { l1 = l[e]; i1 = e; }
        const float p0 = 1.f / (1.f + __expf(l1 - l0));
        const float p1 = 1.f - p0;
        const int pos0 = atomicAdd(&counts[i0], 1);
        lists[i0 * T_TOK + pos0] = (t << 1);
        const int pos1 = atomicAdd(&counts[i1], 1);
        lists[i1 * T_TOK + pos1] = (t << 1) | 1;
        pairw[2 * t]     = p0;
        pairw[2 * t + 1] = p1;
    }
    __syncthreads();
    if (tid < NEXP) atomicAdd(&usage[tid], s_use[tid]);
    if (tid == NEXP) atomicAdd(zacc, s_z);
}

__global__ void finalize_kernel(const int* __restrict__ counts,
                                const float* __restrict__ usage,
                                const float* __restrict__ zacc,
                                int* __restrict__ offs,
                                float* __restrict__ out)
{
    if (threadIdx.x == 0 && blockIdx.x == 0) {
        int o = 0;
        for (int e = 0; e < NEXP; ++e) { offs[e] = o; o += counts[e]; }
        float s = 0.f;
        for (int e = 0; e < NEXP; ++e) {
            const float u = usage[e] / (float)T_TOK;
            s += u * u;
        }
        out[(size_t)T_TOK * DIM]     = (float)NEXP * s;
        out[(size_t)T_TOK * DIM + 1] = zacc[0] / (float)T_TOK;
    }
}

// ---------------------------------------------------------------------------
// Weight conversions (transpose to [n][k] bf16, us4 stores)
// ---------------------------------------------------------------------------
__global__ __launch_bounds__(256) void conv_w1_kernel(
    const float* __restrict__ wg, const float* __restrict__ wu,
    unsigned short* __restrict__ B1)
{
    __shared__ float tg[32][33];
    __shared__ float tu[32][33];
    const int e = blockIdx.z;
    const int h0 = blockIdx.x * 32;
    const int k0 = blockIdx.y * 32;
    const int tid = threadIdx.x;
    const int c = tid & 31, r = tid >> 5;
    const size_t wb = (size_t)e * DIM * HID;
    #pragma unroll
    for (int i = 0; i < 4; ++i) {
        const int kk = r + i * 8;
        const int h = h0 + c;
        float g = 0.f, u = 0.f;
        if (h < HID) {
            const size_t off = wb + (size_t)(k0 + kk) * HID + h;
            g = wg[off]; u = wu[off];
        }
        tg[kk][c] = g; tu[kk][c] = u;
    }
    __syncthreads();
    const int hl = tid >> 3, kq = (tid & 7) * 4;
    us4 vg, vu;
    vg.x = f2bf(tg[kq][hl]);   vg.y = f2bf(tg[kq+1][hl]);
    vg.z = f2bf(tg[kq+2][hl]); vg.w = f2bf(tg[kq+3][hl]);
    vu.x = f2bf(tu[kq][hl]);   vu.y = f2bf(tu[kq+1][hl]);
    vu.z = f2bf(tu[kq+2][hl]); vu.w = f2bf(tu[kq+3][hl]);
    *(us4*)&B1[((size_t)e * NB1 + h0 + hl) * DIM + k0 + kq] = vg;
    *(us4*)&B1[((size_t)e * NB1 + HP2 + h0 + hl) * DIM + k0 + kq] = vu;
}

__global__ __launch_bounds__(256) void conv_w2_kernel(
    const float* __restrict__ wd, unsigned short* __restrict__ B2)
{
    __shared__ float t2[32][33];
    const int e = blockIdx.z;
    const int h0 = blockIdx.x * 32;   // k dim
    const int d0 = blockIdx.y * 32;   // n dim
    const int tid = threadIdx.x;
    const int c = tid & 31, r = tid >> 5;
    const size_t wb = (size_t)e * HID * DIM;
    #pragma unroll
    for (int i = 0; i < 4; ++i) {
        const int kk = r + i * 8;
        const int h = h0 + kk;
        float v = 0.f;
        if (h < HID) v = wd[wb + (size_t)h * DIM + d0 + c];
        t2[kk][c] = v;
    }
    __syncthreads();
    const int dl = tid >> 3, kq = (tid & 7) * 4;
    us4 v;
    v.x = f2bf(t2[kq][dl]);   v.y = f2bf(t2[kq+1][dl]);
    v.z = f2bf(t2[kq+2][dl]); v.w = f2bf(t2[kq+3][dl]);
    *(us4*)&B2[((size_t)e * DIM + d0 + dl) * HP2 + h0 + kq] = v;
}

// ---------------------------------------------------------------------------
// GEMM1 (MFMA, swizzled LDS): h[slot,:] = silu(Xe@Wg)*(Xe@Wu), 128x128x32
// ---------------------------------------------------------------------------
__global__ __launch_bounds__(256, 2) void gemm1_kernel(
    const unsigned short* __restrict__ xb, const unsigned short* __restrict__ B1,
    const int* __restrict__ counts, const int* __restrict__ offs,
    const int* __restrict__ lists, unsigned short* __restrict__ h)
{
    const int e = blockIdx.z;
    const int cnt = counts[e];
    const int row0 = blockIdx.y * 128;
    if (row0 >= cnt) return;
    const int off = offs[e];
    const int n0 = blockIdx.x * 128;

    __shared__ unsigned short s1[12288];   // 24 KB arena: A | Bg | Bu
    __shared__ int s_pr[128];
    unsigned short* sA  = s1;
    unsigned short* sBg = s1 + 4096;
    unsigned short* sBu = s1 + 8192;

    const int tid = threadIdx.x;
    const int w = tid >> 6, lane = tid & 63;
    if (tid < 128) {
        const int r = row0 + tid;
        s_pr[tid] = (r < cnt) ? lists[e * T_TOK + r] : -1;
    }
    __syncthreads();

    // staging: row rA, swizzled source k-block
    const int rA = tid >> 2, kb = tid & 3;
    const int kbs = (kb ^ ((rA >> 1) & 3)) * 8;   // elems
    const int pr0 = s_pr[rA], pr1 = s_pr[rA + 64];
    const unsigned short* agp0 = xb + (size_t)(max(pr0, 0) >> 1) * DIM + kbs;
    const unsigned short* agp1 = xb + (size_t)(max(pr1, 0) >> 1) * DIM + kbs;
    const unsigned short* bgp0 = B1 + ((size_t)e * NB1 + n0 + rA) * DIM + kbs;
    const unsigned short* bgp1 = bgp0 + (size_t)64 * DIM;
    const unsigned short* bup0 = B1 + ((size_t)e * NB1 + HP2 + n0 + rA) * DIM + kbs;
    const unsigned short* bup1 = bup0 + (size_t)64 * DIM;

    char* sAb = (char*)sA; char* sBgb = (char*)sBg; char* sBub = (char*)sBu;
    void* ldsA0 = sAb + w * 1024;        void* ldsA1 = sAb + 4096 + w * 1024;
    void* ldsG0 = sBgb + w * 1024;       void* ldsG1 = sBgb + 4096 + w * 1024;
    void* ldsU0 = sBub + w * 1024;       void* ldsU1 = sBub + 4096 + w * 1024;

    f32x4 accg[4][4], accu[4][4];
    #pragma unroll
    for (int i = 0; i < 4; ++i)
        #pragma unroll
        for (int j = 0; j < 4; ++j) { accg[i][j] = (f32x4)0.f; accu[i][j] = (f32x4)0.f; }

    const int wm = w & 1, wn = w >> 1;
    const int fm = lane & 15, fq = lane >> 4;
    const int kq = (fq ^ ((fm >> 1) & 3)) * 8;    // swizzled fragment k-offset

    for (int kt = 0; kt < DIM / 32; ++kt) {
        const int k0 = kt * 32;
        load_lds16(agp0 + k0, ldsA0);
        load_lds16(agp1 + k0, ldsA1);
        load_lds16(bgp0 + k0, ldsG0);
        load_lds16(bgp1 + k0, ldsG1);
        load_lds16(bup0 + k0, ldsU0);
        load_lds16(bup1 + k0, ldsU1);
        __syncthreads();

        short8 a[4], bg[4], bu[4];
        #pragma unroll
        for (int i = 0; i < 4; ++i) {
            a[i]  = *(const short8*)&sA[(wm * 64 + i * 16 + fm) * 32 + kq];
            bg[i] = *(const short8*)&sBg[(wn * 64 + i * 16 + fm) * 32 + kq];
            bu[i] = *(const short8*)&sBu[(wn * 64 + i * 16 + fm) * 32 + kq];
        }
        #pragma unroll
        for (int i = 0; i < 4; ++i)
            #pragma unroll
            for (int j = 0; j < 4; ++j) {
                accg[i][j] = __builtin_amdgcn_mfma_f32_16x16x32_bf16(a[i], bg[j], accg[i][j], 0, 0, 0);
                accu[i][j] = __builtin_amdgcn_mfma_f32_16x16x32_bf16(a[i], bu[j], accu[i][j], 0, 0, 0);
            }
        __syncthreads();
    }

    // epilogue: silu(g)*u -> LDS bounce (16x64 subtile, stride 72) -> 16B stores
    unsigned short* wbuf = s1 + w * 1152;   // 2304 B per wave
    const int rrow = lane >> 2, cq = (lane & 3) * 16;
    #pragma unroll
    for (int i = 0; i < 4; ++i) {
        #pragma unroll
        for (int j = 0; j < 4; ++j)
            #pragma unroll
            for (int reg = 0; reg < 4; ++reg) {
                const float g = accg[i][j][reg];
                const float u = accu[i][j][reg];
                const float s = g / (1.f + __expf(-g));
                wbuf[(fq * 4 + reg) * 72 + j * 16 + fm] = f2bf(s * u);
            }
        const int rl = wm * 64 + i * 16 + rrow;
        if (row0 + rl < cnt) {
            unsigned short* dst = h + (size_t)(off + row0 + rl) * HP2 + n0 + wn * 64 + cq;
            const short8 v0 = *(const short8*)&wbuf[rrow * 72 + cq];
            const short8 v1 = *(const short8*)&wbuf[rrow * 72 + cq + 8];
            *(short8*)dst = v0;
            *(short8*)(dst + 8) = v1;
        }
    }
}

// ---------------------------------------------------------------------------
// GEMM2 (MFMA, swizzled LDS): op[pr,:] = h_slot @ Wd, 128x128x32, K=2816
// ---------------------------------------------------------------------------
__global__ __launch_bounds__(256, 2) void gemm2_kernel(
    const unsigned short* __restrict__ h, const unsigned short* __restrict__ B2,
    const int* __restrict__ counts, const int* __restrict__ offs,
    const int* __restrict__ lists, unsigned short* __restrict__ op)
{
    const int e = blockIdx.z;
    const int cnt = counts[e];
    const int row0 = blockIdx.y * 128;
    if (row0 >= cnt) return;
    const int off = offs[e];
    const int n0 = blockIdx.x * 128;

    __shared__ unsigned short s2[8192];    // 16 KB arena: A | B
    __shared__ int s_pr[128];
    unsigned short* sA = s2;
    unsigned short* sB = s2 + 4096;

    const int tid = threadIdx.x;
    const int w = tid >> 6, lane = tid & 63;
    if (tid < 128) {
        const int r = row0 + tid;
        s_pr[tid] = (r < cnt) ? lists[e * T_TOK + r] : -1;
    }
    __syncthreads();

    const int rA = tid >> 2, kb = tid & 3;
    const int kbs = (kb ^ ((rA >> 1) & 3)) * 8;
    const unsigned short* agp0 = h + (size_t)(off + row0 + rA) * HP2 + kbs;
    const unsigned short* agp1 = agp0 + (size_t)64 * HP2;
    const unsigned short* bp0 = B2 + ((size_t)e * DIM + n0 + rA) * HP2 + kbs;
    const unsigned short* bp1 = bp0 + (size_t)64 * HP2;

    char* sAb = (char*)sA; char* sBb = (char*)sB;
    void* ldsA0 = sAb + w * 1024;  void* ldsA1 = sAb + 4096 + w * 1024;
    void* ldsB0 = sBb + w * 1024;  void* ldsB1 = sBb + 4096 + w * 1024;

    f32x4 acc[4][4];
    #pragma unroll
    for (int i = 0; i < 4; ++i)
        #pragma unroll
        for (int j = 0; j < 4; ++j) acc[i][j] = (f32x4)0.f;

    const int wm = w & 1, wn = w >> 1;
    const int fm = lane & 15, fq = lane >> 4;
    const int kq = (fq ^ ((fm >> 1) & 3)) * 8;

    for (int kt = 0; kt < HP2 / 32; ++kt) {
        const int k0 = kt * 32;
        load_lds16(agp0 + k0, ldsA0);
        load_lds16(agp1 + k0, ldsA1);
        load_lds16(bp0 + k0, ldsB0);
        load_lds16(bp1 + k0, ldsB1);
        __syncthreads();

        short8 a[4], b[4];
        #pragma unroll
        for (int i = 0; i < 4; ++i) {
            a[i] = *(const short8*)&sA[(wm * 64 + i * 16 + fm) * 32 + kq];
            b[i] = *(const short8*)&sB[(wn * 64 + i * 16 + fm) * 32 + kq];
        }
        #pragma unroll
        for (int i = 0; i < 4; ++i)
            #pragma unroll
            for (int j = 0; j < 4; ++j)
                acc[i][j] = __builtin_amdgcn_mfma_f32_16x16x32_bf16(a[i], b[j], acc[i][j], 0, 0, 0);
        __syncthreads();
    }

    // epilogue: LDS bounce, scatter rows by pair id (bf16 op)
    unsigned short* wbuf = s2 + w * 1152;
    const int rrow = lane >> 2, cq = (lane & 3) * 16;
    #pragma unroll
    for (int i = 0; i < 4; ++i) {
        #pragma unroll
        for (int j = 0; j < 4; ++j)
            #pragma unroll
            for (int reg = 0; reg < 4; ++reg)
                wbuf[(fq * 4 + reg) * 72 + j * 16 + fm] = f2bf(acc[i][j][reg]);
        const int rl = wm * 64 + i * 16 + rrow;
        const int pr = s_pr[rl];
        if (pr >= 0) {
            unsigned short* dst = op + (size_t)pr * DIM + n0 + wn * 64 + cq;
            const short8 v0 = *(const short8*)&wbuf[rrow * 72 + cq];
            const short8 v1 = *(const short8*)&wbuf[rrow * 72 + cq + 8];
            *(short8*)dst = v0;
            *(short8*)(dst + 8) = v1;
        }
    }
}

// ---------------------------------------------------------------------------
// Combine: out[t] = w0*op[2t] + w1*op[2t+1]  (op bf16 -> out f32)
// ---------------------------------------------------------------------------
__global__ __launch_bounds__(256) void combine_kernel(
    const unsigned short* __restrict__ op, const float* __restrict__ pairw,
    float* __restrict__ out)
{
    const int f = blockIdx.x * 256 + threadIdx.x;   // over T*D/4
    const int t = f >> 8;
    const int c = f & 255;
    const float w0 = pairw[2 * t], w1 = pairw[2 * t + 1];
    const us4 a = ((const us4*)op)[(size_t)(2 * t) * (DIM / 4) + c];
    const us4 b = ((const us4*)op)[(size_t)(2 * t + 1) * (DIM / 4) + c];
    float4 r;
    r.x = w0 * __uint_as_float((unsigned)a.x << 16) + w1 * __uint_as_float((unsigned)b.x << 16);
    r.y = w0 * __uint_as_float((unsigned)a.y << 16) + w1 * __uint_as_float((unsigned)b.y << 16);
    r.z = w0 * __uint_as_float((unsigned)a.z << 16) + w1 * __uint_as_float((unsigned)b.z << 16);
    r.w = w0 * __uint_as_float((unsigned)a.w << 16) + w1 * __uint_as_float((unsigned)b.w << 16);
    ((float4*)out)[f] = r;
}

extern "C" void kernel_launch(void* const* d_in, const int* in_sizes, int n_in,
                              void* d_out, int out_size, void* d_ws, size_t ws_size,
                              hipStream_t stream)
{
    const float* x  = (const float*)d_in[0];
    const float* rw = (const float*)d_in[1];
    const float* wg = (const float*)d_in[2];
    const float* wu = (const float*)d_in[3];
    const float* wd = (const float*)d_in[4];
    float* out = (float*)d_out;
    char* ws = (char*)d_ws;

    int*   counts = (int*)(ws + OFF_CNT);
    float* usage  = (float*)(ws + OFF_USE);
    float* zacc   = (float*)(ws + OFF_Z);
    int*   offs   = (int*)(ws + OFF_OFFS);
    int*   lists  = (int*)(ws + OFF_LIST);
    float* pairw  = (float*)(ws + OFF_PAIRW);
    unsigned short* xb  = (unsigned short*)(ws + OFF_XB);
    unsigned short* hb  = (unsigned short*)(ws + OFF_H);
    unsigned short* B2  = (unsigned short*)(ws + OFF_B2);
    unsigned short* B1  = (unsigned short*)(ws + OFF_B1);
    unsigned short* op  = (unsigned short*)(ws + OFF_OP);

    hipMemsetAsync(ws, 0, 128, stream);

    router_kernel<<<T_TOK / 4, 256, 0, stream>>>(x, rw, counts, usage, zacc, lists, pairw, xb);
    finalize_kernel<<<1, 64, 0, stream>>>(counts, usage, zacc, offs, out);

    conv_w1_kernel<<<dim3(HP2 / 32, DIM / 32, NEXP), 256, 0, stream>>>(wg, wu, B1);
    conv_w2_kernel<<<dim3(HP2 / 32, DIM / 32, NEXP), 256, 0, stream>>>(wd, B2);

    gemm1_kernel<<<dim3(HP2 / 128, T_TOK / 128, NEXP), 256, 0, stream>>>(xb, B1, counts, offs, lists, hb);
    gemm2_kernel<<<dim3(DIM / 128, T_TOK / 128, NEXP), 256, 0, stream>>>(hb, B2, counts, offs, lists, op);

    combine_kernel<<<(T_TOK * DIM / 4) / 256, 256, 0, stream>>>(op, pairw, out);
}